// Round 1
// baseline (827.287 us; speedup 1.0000x reference)
//
#include <hip/hip_runtime.h>

#define THREADS 256

__device__ __forceinline__ unsigned score_key(float s) {
    unsigned u = __float_as_uint(s);
    return (u & 0x80000000u) ? ~u : (u | 0x80000000u);
}

// v[j] = sum_o W2[j,o]*Ws[o];  v[256] = dot(b2,Ws) + bs
__global__ void prep_kernel(const float* __restrict__ W2, const float* __restrict__ b2,
                            const float* __restrict__ Ws, const float* __restrict__ bs,
                            float* __restrict__ v, int OUT) {
    int j = threadIdx.x;
    float acc = 0.f;
    for (int o = 0; o < OUT; ++o) acc += W2[j * OUT + o] * Ws[o];
    v[j] = acc;
    if (j == 0) {
        float c = bs[0];
        for (int o = 0; o < OUT; ++o) c += b2[o] * Ws[o];
        v[256] = c;
    }
}

__global__ void init_bins(unsigned long long* __restrict__ bins, int n) {
    int i = blockIdx.x * blockDim.x + threadIdx.x;
    if (i < n) bins[i] = 0ULL;
}

// Fused: h = desc@W1 + b1 ; LN ; SiLU ; score = h.v + c ; gid ; per-bin atomic argmax
__global__ __launch_bounds__(256) void score_kernel(
    const float* __restrict__ desc, const float* __restrict__ kpts,
    const float* __restrict__ W1, const float* __restrict__ b1,
    const float* __restrict__ g1, const float* __restrict__ be1,
    const int* __restrict__ Hp, const int* __restrict__ Wp,
    const float* __restrict__ v,
    float* __restrict__ scores, unsigned long long* __restrict__ bins,
    int N, int total)
{
    __shared__ float dsL[64][36];      // desc tile, stride 36: bank-conflict-free, 16B aligned rows
    __shared__ float w1L[32][256];     // W1 tile
    __shared__ float b1L[256], g1L[256], beL[256], vL[256];

    const int t = threadIdx.x;
    const int p = t >> 3;      // 0..31 (point within first half)
    const int db = t & 7;      // dim group 0..7 (32 dims each)
    const int row0 = blockIdx.x * 64;

    b1L[t] = b1[t]; g1L[t] = g1[t]; beL[t] = be1[t]; vL[t] = v[t];
    __syncthreads();

    float4 acc0[8], acc1[8];
#pragma unroll
    for (int i = 0; i < 8; ++i) {
        const int c = (i + db) & 7;
        const float4 bv = *(const float4*)&b1L[db * 32 + c * 4];
        acc0[i] = bv; acc1[i] = bv;
    }

    const int cc = t & 7;
    for (int kt = 0; kt < 8; ++kt) {
        // stage desc [64 x 32]
        {
            const int rA = min(row0 + p, total - 1);
            const int rB = min(row0 + p + 32, total - 1);
            *(float4*)&dsL[p][cc * 4] =
                *(const float4*)&desc[(size_t)rA * 256 + kt * 32 + cc * 4];
            *(float4*)&dsL[p + 32][cc * 4] =
                *(const float4*)&desc[(size_t)rB * 256 + kt * 32 + cc * 4];
        }
        // stage W1 [32 x 256]
        {
            const int col4 = t & 63;
            const int kr0 = t >> 6;
#pragma unroll
            for (int l = 0; l < 8; ++l) {
                const int kr = kr0 + l * 4;
                *(float4*)&w1L[kr][col4 * 4] =
                    *(const float4*)&W1[(size_t)(kt * 32 + kr) * 256 + col4 * 4];
            }
        }
        __syncthreads();
#pragma unroll
        for (int kk = 0; kk < 32; ++kk) {
            const float a0 = dsL[p][kk];
            const float a1 = dsL[p + 32][kk];
            const float4* wrow = (const float4*)&w1L[kk][db * 32];
#pragma unroll
            for (int i = 0; i < 8; ++i) {
                const int c = (i + db) & 7;
                const float4 w = wrow[c];
                acc0[i].x = fmaf(a0, w.x, acc0[i].x);
                acc0[i].y = fmaf(a0, w.y, acc0[i].y);
                acc0[i].z = fmaf(a0, w.z, acc0[i].z);
                acc0[i].w = fmaf(a0, w.w, acc0[i].w);
                acc1[i].x = fmaf(a1, w.x, acc1[i].x);
                acc1[i].y = fmaf(a1, w.y, acc1[i].y);
                acc1[i].z = fmaf(a1, w.z, acc1[i].z);
                acc1[i].w = fmaf(a1, w.w, acc1[i].w);
            }
        }
        __syncthreads();
    }

    // ---- LayerNorm + SiLU + dot(v), per point, across the 8 db lanes ----
    float s0 = 0.f, s1 = 0.f;
#pragma unroll
    for (int i = 0; i < 8; ++i) {
        s0 += acc0[i].x + acc0[i].y + acc0[i].z + acc0[i].w;
        s1 += acc1[i].x + acc1[i].y + acc1[i].z + acc1[i].w;
    }
    s0 += __shfl_xor(s0, 1); s0 += __shfl_xor(s0, 2); s0 += __shfl_xor(s0, 4);
    s1 += __shfl_xor(s1, 1); s1 += __shfl_xor(s1, 2); s1 += __shfl_xor(s1, 4);
    const float mu0 = s0 * (1.0f / 256.0f);
    const float mu1 = s1 * (1.0f / 256.0f);

    float q0 = 0.f, q1 = 0.f;
#pragma unroll
    for (int i = 0; i < 8; ++i) {
        const float* a0 = (const float*)&acc0[i];
        const float* a1 = (const float*)&acc1[i];
#pragma unroll
        for (int q = 0; q < 4; ++q) {
            float d0 = a0[q] - mu0; q0 = fmaf(d0, d0, q0);
            float d1 = a1[q] - mu1; q1 = fmaf(d1, d1, q1);
        }
    }
    q0 += __shfl_xor(q0, 1); q0 += __shfl_xor(q0, 2); q0 += __shfl_xor(q0, 4);
    q1 += __shfl_xor(q1, 1); q1 += __shfl_xor(q1, 2); q1 += __shfl_xor(q1, 4);
    const float r0 = 1.0f / sqrtf(q0 * (1.0f / 256.0f) + 1e-5f);
    const float r1 = 1.0f / sqrtf(q1 * (1.0f / 256.0f) + 1e-5f);

    float dot0 = 0.f, dot1 = 0.f;
#pragma unroll
    for (int i = 0; i < 8; ++i) {
        const int c = (i + db) & 7;
        const int j = db * 32 + c * 4;
        const float* a0 = (const float*)&acc0[i];
        const float* a1 = (const float*)&acc1[i];
#pragma unroll
        for (int q = 0; q < 4; ++q) {
            const float g = g1L[j + q], be = beL[j + q], vv = vL[j + q];
            const float y0 = (a0[q] - mu0) * r0 * g + be;
            dot0 = fmaf(vv, y0 / (1.f + expf(-y0)), dot0);
            const float y1 = (a1[q] - mu1) * r1 * g + be;
            dot1 = fmaf(vv, y1 / (1.f + expf(-y1)), dot1);
        }
    }
    dot0 += __shfl_xor(dot0, 1); dot0 += __shfl_xor(dot0, 2); dot0 += __shfl_xor(dot0, 4);
    dot1 += __shfl_xor(dot1, 1); dot1 += __shfl_xor(dot1, 2); dot1 += __shfl_xor(dot1, 4);

    if (db == 0) {
        const float Wf = (float)Wp[0];
        const int Hi = Hp[0];
        const float t02 = (float)(0.2 * (double)Hi);
        const float t05 = (float)(0.5 * (double)Hi);
        const float t03 = (float)(0.3 * (double)Hi);
        const float cterm = v[256];
#pragma unroll
        for (int pt = 0; pt < 2; ++pt) {
            const int row = row0 + p + pt * 32;
            if (row >= total) break;
            const float sc = (pt ? dot1 : dot0) + cterm;
            scores[row] = sc;
            const float x = kpts[(size_t)row * 2 + 0];
            const float y = kpts[(size_t)row * 2 + 1];
            int g = -1;
            if (y > t05) {
                int bgx = (int)(x / Wf * 16.f); bgx = min(max(bgx, 0), 15);
                int bgy = (int)((y - t05) / t05 * 6.f); bgy = min(max(bgy, 0), 5);
                g = 32 + bgy * 16 + bgx;
            } else if (y > t02) {
                int mgx = (int)(x / Wf * 8.f); mgx = min(max(mgx, 0), 7);
                int mgy = (int)((y - t02) / t03 * 4.f); mgy = min(max(mgy, 0), 3);
                g = mgy * 8 + mgx;
            }
            if (g >= 0) {
                const int bb = row / N;
                const int n = row - bb * N;
                const unsigned long long pk =
                    ((unsigned long long)score_key(sc) << 32) | (unsigned)(~(unsigned)n);
                atomicMax(&bins[bb * 128 + g], pk);
            }
        }
    }
}

// One block per batch: compact bin winners (bin order), top-k fallback, gather outputs.
__global__ __launch_bounds__(256) void finalize_kernel(
    const float* __restrict__ scores, const unsigned long long* __restrict__ bins,
    const float* __restrict__ desc, const float* __restrict__ kpts,
    const int* __restrict__ tkp, float* __restrict__ out, int B, int N)
{
    const int b = blockIdx.x, t = threadIdx.x;
    const int topk = tkp[0];
    __shared__ int selL[512];
    __shared__ int nselS;
    __shared__ unsigned long long red[256];
    __shared__ unsigned long long binL[128];

    if (t < 128) binL[t] = bins[b * 128 + t];
    __syncthreads();
    if (t == 0) {
        int c = 0;
        for (int i = 0; i < 128; ++i)
            if ((binL[i] >> 32) != 0ULL) selL[c++] = (int)(~(unsigned)binL[i]);
        nselS = c;
    }
    __syncthreads();
    const int nsel = nselS;

    // fallback top-k on remaining (never runs for this dataset: all 128 bins occupied)
    for (int need = nsel; need < topk; ++need) {
        unsigned long long best = 0ULL;
        for (int i = t; i < N; i += THREADS) {
            bool taken = false;
            for (int s2 = 0; s2 < need; ++s2)
                if (selL[s2] == i) { taken = true; break; }
            if (!taken) {
                const unsigned long long pk =
                    ((unsigned long long)score_key(scores[(size_t)b * N + i]) << 32)
                    | (unsigned)(~(unsigned)i);
                if (pk > best) best = pk;
            }
        }
        red[t] = best;
        __syncthreads();
        for (int off = 128; off > 0; off >>= 1) {
            if (t < off) { if (red[t + off] > red[t]) red[t] = red[t + off]; }
            __syncthreads();
        }
        if (t == 0) selL[need] = (int)(~(unsigned)red[0]);
        __syncthreads();
    }

    // gather outputs (all float32; indices written as float values)
    float* o_feat = out;
    float* o_kpts = out + (size_t)B * topk * 256;
    float* o_idx  = out + (size_t)B * topk * 258;
    for (int e = t; e < topk * 64; e += THREADS) {
        const int j = e >> 6, q4 = e & 63;
        const int n = selL[j];
        *(float4*)&o_feat[((size_t)b * topk + j) * 256 + q4 * 4] =
            *(const float4*)&desc[((size_t)b * N + n) * 256 + q4 * 4];
    }
    for (int j = t; j < topk; j += THREADS) {
        const int n = selL[j];
        o_kpts[((size_t)b * topk + j) * 2 + 0] = kpts[((size_t)b * N + n) * 2 + 0];
        o_kpts[((size_t)b * topk + j) * 2 + 1] = kpts[((size_t)b * N + n) * 2 + 1];
        o_idx[(size_t)b * topk + j] = (float)n;
    }
}

extern "C" void kernel_launch(void* const* d_in, const int* in_sizes, int n_in,
                              void* d_out, int out_size, void* d_ws, size_t ws_size,
                              hipStream_t stream) {
    const float* kpts = (const float*)d_in[0];
    const float* desc = (const float*)d_in[1];
    const int*   Hp   = (const int*)d_in[2];
    const int*   Wp   = (const int*)d_in[3];
    const int*   tkp  = (const int*)d_in[4];
    const float* W1   = (const float*)d_in[5];
    const float* b1   = (const float*)d_in[6];
    const float* g1   = (const float*)d_in[7];
    const float* be1  = (const float*)d_in[8];
    const float* W2   = (const float*)d_in[9];
    const float* b2   = (const float*)d_in[10];
    const float* Ws   = (const float*)d_in[11];
    const float* bs   = (const float*)d_in[12];

    const int total = in_sizes[1] / 256;   // B*N
    const int BT    = out_size / 259;      // B*topk
    const int B     = BT / 128;            // topk = 128 for this problem
    const int N     = total / B;
    const int OUT   = in_sizes[11];        // 128

    float* ws_v      = (float*)d_ws;                       // 257 floats (pad 512)
    float* ws_scores = ws_v + 512;                         // total floats
    size_t binoff = ((size_t)(512 + total) * 4 + 7) & ~(size_t)7;
    unsigned long long* ws_bins = (unsigned long long*)((char*)d_ws + binoff);

    prep_kernel<<<1, 256, 0, stream>>>(W2, b2, Ws, bs, ws_v, OUT);
    init_bins<<<(B * 128 + 255) / 256, 256, 0, stream>>>(ws_bins, B * 128);
    score_kernel<<<(total + 63) / 64, 256, 0, stream>>>(
        desc, kpts, W1, b1, g1, be1, Hp, Wp, ws_v, ws_scores, ws_bins, N, total);
    finalize_kernel<<<B, 256, 0, stream>>>(ws_scores, ws_bins, desc, kpts, tkp,
                                           (float*)d_out, B, N);
}

// Round 2
// 419.883 us; speedup vs baseline: 1.9703x; 1.9703x over previous
//
#include <hip/hip_runtime.h>

#define THREADS 256

typedef short bf16x8 __attribute__((ext_vector_type(8)));
typedef float f32x4 __attribute__((ext_vector_type(4)));

__device__ __forceinline__ unsigned short f2bf(float x) {
    unsigned u = __float_as_uint(x);
    unsigned r = u + 0x7FFFu + ((u >> 16) & 1u);
    return (unsigned short)(r >> 16);
}
__device__ __forceinline__ float bf2f(unsigned short h) {
    return __uint_as_float(((unsigned)h) << 16);
}
__device__ __forceinline__ unsigned score_key(float s) {
    unsigned u = __float_as_uint(s);
    return (u & 0x80000000u) ? ~u : (u | 0x80000000u);
}

// v[j] = sum_o W2[j,o]*Ws[o];  v[256] = dot(b2,Ws) + bs
__global__ void prep_kernel(const float* __restrict__ W2, const float* __restrict__ b2,
                            const float* __restrict__ Ws, const float* __restrict__ bs,
                            float* __restrict__ v, int OUT) {
    int j = threadIdx.x;
    float acc = 0.f;
    for (int o = 0; o < OUT; ++o) acc += W2[j * OUT + o] * Ws[o];
    v[j] = acc;
    if (j == 0) {
        float c = bs[0];
        for (int o = 0; o < OUT; ++o) c += b2[o] * Ws[o];
        v[256] = c;
    }
}

// W1 [256][256] -> fragment-packed bf16 hi/lo: uint4 index = kt*2048 + (h*16+nt)*64 + lane
// element j of slot = W1[kt*32 + (lane>>4)*8 + j][nt*16 + (lane&15)]
__global__ void prep_w1frag(const float* __restrict__ W1, uint4* __restrict__ wfrag) {
    const int s = blockIdx.x * 256 + threadIdx.x;   // 0..16383
    const int rem = s & 2047;
    const int kt = s >> 11;
    const int c = rem >> 6;
    const int lane = rem & 63;
    const int h = c >> 4;
    const int nt = c & 15;
    const int col = nt * 16 + (lane & 15);
    const int kb = kt * 32 + (lane >> 4) * 8;
    unsigned pk[4];
#pragma unroll
    for (int q = 0; q < 4; ++q) {
        float x0 = W1[(size_t)(kb + 2 * q) * 256 + col];
        float x1 = W1[(size_t)(kb + 2 * q + 1) * 256 + col];
        unsigned short a0, a1;
        if (h == 0) { a0 = f2bf(x0); a1 = f2bf(x1); }
        else {
            a0 = f2bf(x0 - bf2f(f2bf(x0)));
            a1 = f2bf(x1 - bf2f(f2bf(x1)));
        }
        pk[q] = (unsigned)a0 | ((unsigned)a1 << 16);
    }
    wfrag[s] = make_uint4(pk[0], pk[1], pk[2], pk[3]);
}

__global__ void init_bins(unsigned long long* __restrict__ bins, int n) {
    int i = blockIdx.x * blockDim.x + threadIdx.x;
    if (i < n) bins[i] = 0ULL;
}

// Fused: h = desc@W1 + b1 (bf16x4-split MFMA); LN; SiLU; score = h.v + c; gid; bin argmax
__global__ __launch_bounds__(256, 2) void score_kernel(
    const float* __restrict__ desc, const float* __restrict__ kpts,
    const uint4* __restrict__ wfrag,
    const float* __restrict__ b1, const float* __restrict__ g1, const float* __restrict__ be1,
    const int* __restrict__ Hp, const int* __restrict__ Wp,
    const float* __restrict__ v,
    float* __restrict__ scores, unsigned long long* __restrict__ bins,
    int N, int total)
{
    __shared__ uint4 AhS[8 * 64];      // desc hi frags: [rowgrp][lane] 16B — 8KB
    __shared__ uint4 AlS[8 * 64];      // desc lo frags — 8KB
    __shared__ uint4 BS[32 * 64];      // W1 frags: chunks 0..15 hi, 16..31 lo — 32KB
    __shared__ float b1L[256], g1L[256], beL[256], vL[256];
    __shared__ float sumsL[128][2];
    __shared__ float ctermS;

    const int t = threadIdx.x;
    const int lane = t & 63;
    const int w = t >> 6;
    const int wm = w & 1, wn = w >> 1;
    const int row0 = blockIdx.x * 128;
    const int l15 = lane & 15, q4 = lane >> 4, h5 = lane >> 5;

    b1L[t] = b1[t]; g1L[t] = g1[t]; beL[t] = be1[t]; vL[t] = v[t];
    if (t == 0) ctermS = v[256];

    f32x4 acc[4][8];
#pragma unroll
    for (int m = 0; m < 4; ++m)
#pragma unroll
        for (int n = 0; n < 8; ++n) acc[m][n] = (f32x4){0.f, 0.f, 0.f, 0.f};

    // A staging geometry: wave w stages rowgrps {2w, 2w+1}
    const int argp = 2 * w + h5;
    const int arow = row0 + argp * 16 + l15;
    const int arowc = min(arow, total - 1);
    const int kgbit = q4 & 1;

    for (int kt = 0; kt < 8; ++kt) {
        __syncthreads();
        // ---- stage B (pre-split W1 frags, 32KB, coalesced copy)
        {
            uint4 btmp[8];
            const uint4* bsrc = wfrag + (size_t)kt * 2048 + t;
#pragma unroll
            for (int j = 0; j < 8; ++j) btmp[j] = bsrc[j * 256];
#pragma unroll
            for (int j = 0; j < 8; ++j) BS[j * 256 + t] = btmp[j];
        }
        // ---- stage A: load fp32, split to bf16 hi/lo, write fragment-linear
#pragma unroll
        for (int i = 0; i < 2; ++i) {
            const int kg = kgbit + 2 * i;
            const float* gp = desc + (size_t)arowc * 256 + kt * 32 + kg * 8;
            float4 f0 = *(const float4*)gp;
            float4 f1 = *(const float4*)(gp + 4);
            float f[8] = {f0.x, f0.y, f0.z, f0.w, f1.x, f1.y, f1.z, f1.w};
            unsigned hs[4], ls[4];
#pragma unroll
            for (int q = 0; q < 4; ++q) {
                unsigned short h0 = f2bf(f[2 * q]), h1 = f2bf(f[2 * q + 1]);
                unsigned short o0 = f2bf(f[2 * q] - bf2f(h0));
                unsigned short o1 = f2bf(f[2 * q + 1] - bf2f(h1));
                hs[q] = (unsigned)h0 | ((unsigned)h1 << 16);
                ls[q] = (unsigned)o0 | ((unsigned)o1 << 16);
            }
            const int slot = argp * 64 + kg * 16 + l15;
            AhS[slot] = make_uint4(hs[0], hs[1], hs[2], hs[3]);
            AlS[slot] = make_uint4(ls[0], ls[1], ls[2], ls[3]);
        }
        __syncthreads();
        // ---- MFMA: 4-pass split-precision
        bf16x8 ah[4], al[4];
#pragma unroll
        for (int m = 0; m < 4; ++m) {
            ah[m] = *(const bf16x8*)&AhS[(wm * 4 + m) * 64 + lane];
            al[m] = *(const bf16x8*)&AlS[(wm * 4 + m) * 64 + lane];
        }
#pragma unroll
        for (int n = 0; n < 8; ++n) {
            const int nt = wn * 8 + n;
            bf16x8 bh = *(const bf16x8*)&BS[nt * 64 + lane];
            bf16x8 bl = *(const bf16x8*)&BS[(16 + nt) * 64 + lane];
#pragma unroll
            for (int m = 0; m < 4; ++m) {
                acc[m][n] = __builtin_amdgcn_mfma_f32_16x16x32_bf16(ah[m], bh, acc[m][n], 0, 0, 0);
                acc[m][n] = __builtin_amdgcn_mfma_f32_16x16x32_bf16(ah[m], bl, acc[m][n], 0, 0, 0);
                acc[m][n] = __builtin_amdgcn_mfma_f32_16x16x32_bf16(al[m], bh, acc[m][n], 0, 0, 0);
                acc[m][n] = __builtin_amdgcn_mfma_f32_16x16x32_bf16(al[m], bl, acc[m][n], 0, 0, 0);
            }
        }
    }

    // ---- Epilogue: LN + SiLU + score, rows = wm*64 + m*16 + q4*4 + r, cols = wn*128 + n*16 + l15
    float bpart = 0.f;
#pragma unroll
    for (int n = 0; n < 8; ++n) bpart += b1L[wn * 128 + n * 16 + l15];

    float mu[4][4], rs[4][4];
    // pass 1: mean
#pragma unroll
    for (int m = 0; m < 4; ++m)
#pragma unroll
        for (int r = 0; r < 4; ++r) {
            float x = bpart;
#pragma unroll
            for (int n = 0; n < 8; ++n) x += acc[m][n][r];
#pragma unroll
            for (int mask = 1; mask <= 8; mask <<= 1) x += __shfl_xor(x, mask);
            if (l15 == 0) sumsL[wm * 64 + m * 16 + q4 * 4 + r][wn] = x;
        }
    __syncthreads();
#pragma unroll
    for (int m = 0; m < 4; ++m)
#pragma unroll
        for (int r = 0; r < 4; ++r) {
            const int rl = wm * 64 + m * 16 + q4 * 4 + r;
            mu[m][r] = (sumsL[rl][0] + sumsL[rl][1]) * (1.f / 256.f);
        }
    __syncthreads();
    // pass 2: variance
#pragma unroll
    for (int m = 0; m < 4; ++m)
#pragma unroll
        for (int r = 0; r < 4; ++r) {
            float x = 0.f;
#pragma unroll
            for (int n = 0; n < 8; ++n) {
                const float hv = acc[m][n][r] + b1L[wn * 128 + n * 16 + l15] - mu[m][r];
                x = fmaf(hv, hv, x);
            }
#pragma unroll
            for (int mask = 1; mask <= 8; mask <<= 1) x += __shfl_xor(x, mask);
            if (l15 == 0) sumsL[wm * 64 + m * 16 + q4 * 4 + r][wn] = x;
        }
    __syncthreads();
#pragma unroll
    for (int m = 0; m < 4; ++m)
#pragma unroll
        for (int r = 0; r < 4; ++r) {
            const int rl = wm * 64 + m * 16 + q4 * 4 + r;
            rs[m][r] = 1.f / sqrtf((sumsL[rl][0] + sumsL[rl][1]) * (1.f / 256.f) + 1e-5f);
        }
    __syncthreads();
    // pass 3: score = sum_c v[c] * SiLU(LN(h))
#pragma unroll
    for (int m = 0; m < 4; ++m)
#pragma unroll
        for (int r = 0; r < 4; ++r) {
            float x = 0.f;
#pragma unroll
            for (int n = 0; n < 8; ++n) {
                const int c = wn * 128 + n * 16 + l15;
                const float hv = (acc[m][n][r] + b1L[c] - mu[m][r]) * rs[m][r] * g1L[c] + beL[c];
                const float sg = 1.f / (1.f + __expf(-hv));
                x = fmaf(vL[c], hv * sg, x);
            }
#pragma unroll
            for (int mask = 1; mask <= 8; mask <<= 1) x += __shfl_xor(x, mask);
            if (l15 == 0) sumsL[wm * 64 + m * 16 + q4 * 4 + r][wn] = x;
        }
    __syncthreads();

    if (t < 128) {
        const int row = row0 + t;
        if (row < total) {
            const float sc = sumsL[t][0] + sumsL[t][1] + ctermS;
            scores[row] = sc;
            const float Wf = (float)Wp[0];
            const int Hi = Hp[0];
            const float t02 = (float)(0.2 * (double)Hi);
            const float t05 = (float)(0.5 * (double)Hi);
            const float t03 = (float)(0.3 * (double)Hi);
            const float x = kpts[(size_t)row * 2 + 0];
            const float y = kpts[(size_t)row * 2 + 1];
            int g = -1;
            if (y > t05) {
                int bgx = (int)(x / Wf * 16.f); bgx = min(max(bgx, 0), 15);
                int bgy = (int)((y - t05) / t05 * 6.f); bgy = min(max(bgy, 0), 5);
                g = 32 + bgy * 16 + bgx;
            } else if (y > t02) {
                int mgx = (int)(x / Wf * 8.f); mgx = min(max(mgx, 0), 7);
                int mgy = (int)((y - t02) / t03 * 4.f); mgy = min(max(mgy, 0), 3);
                g = mgy * 8 + mgx;
            }
            if (g >= 0) {
                const int bb = row / N;
                const int n = row - bb * N;
                const unsigned long long pk =
                    ((unsigned long long)score_key(sc) << 32) | (unsigned)(~(unsigned)n);
                atomicMax(&bins[bb * 128 + g], pk);
            }
        }
    }
}

// One block per batch: compact bin winners (bin order), top-k fallback, gather outputs.
__global__ __launch_bounds__(256) void finalize_kernel(
    const float* __restrict__ scores, const unsigned long long* __restrict__ bins,
    const float* __restrict__ desc, const float* __restrict__ kpts,
    const int* __restrict__ tkp, float* __restrict__ out, int B, int N)
{
    const int b = blockIdx.x, t = threadIdx.x;
    const int topk = tkp[0];
    __shared__ int selL[512];
    __shared__ int nselS;
    __shared__ unsigned long long red[256];
    __shared__ unsigned long long binL[128];

    if (t < 128) binL[t] = bins[b * 128 + t];
    __syncthreads();
    if (t == 0) {
        int c = 0;
        for (int i = 0; i < 128; ++i)
            if ((binL[i] >> 32) != 0ULL) selL[c++] = (int)(~(unsigned)binL[i]);
        nselS = c;
    }
    __syncthreads();
    const int nsel = nselS;

    for (int need = nsel; need < topk; ++need) {
        unsigned long long best = 0ULL;
        for (int i = t; i < N; i += THREADS) {
            bool taken = false;
            for (int s2 = 0; s2 < need; ++s2)
                if (selL[s2] == i) { taken = true; break; }
            if (!taken) {
                const unsigned long long pk =
                    ((unsigned long long)score_key(scores[(size_t)b * N + i]) << 32)
                    | (unsigned)(~(unsigned)i);
                if (pk > best) best = pk;
            }
        }
        red[t] = best;
        __syncthreads();
        for (int off = 128; off > 0; off >>= 1) {
            if (t < off) { if (red[t + off] > red[t]) red[t] = red[t + off]; }
            __syncthreads();
        }
        if (t == 0) selL[need] = (int)(~(unsigned)red[0]);
        __syncthreads();
    }

    float* o_feat = out;
    float* o_kpts = out + (size_t)B * topk * 256;
    float* o_idx  = out + (size_t)B * topk * 258;
    for (int e = t; e < topk * 64; e += THREADS) {
        const int j = e >> 6, q4 = e & 63;
        const int n = selL[j];
        *(float4*)&o_feat[((size_t)b * topk + j) * 256 + q4 * 4] =
            *(const float4*)&desc[((size_t)b * N + n) * 256 + q4 * 4];
    }
    for (int j = t; j < topk; j += THREADS) {
        const int n = selL[j];
        o_kpts[((size_t)b * topk + j) * 2 + 0] = kpts[((size_t)b * N + n) * 2 + 0];
        o_kpts[((size_t)b * topk + j) * 2 + 1] = kpts[((size_t)b * N + n) * 2 + 1];
        o_idx[(size_t)b * topk + j] = (float)n;
    }
}

extern "C" void kernel_launch(void* const* d_in, const int* in_sizes, int n_in,
                              void* d_out, int out_size, void* d_ws, size_t ws_size,
                              hipStream_t stream) {
    const float* kpts = (const float*)d_in[0];
    const float* desc = (const float*)d_in[1];
    const int*   Hp   = (const int*)d_in[2];
    const int*   Wp   = (const int*)d_in[3];
    const int*   tkp  = (const int*)d_in[4];
    const float* W1   = (const float*)d_in[5];
    const float* b1   = (const float*)d_in[6];
    const float* g1   = (const float*)d_in[7];
    const float* be1  = (const float*)d_in[8];
    const float* W2   = (const float*)d_in[9];
    const float* b2   = (const float*)d_in[10];
    const float* Ws   = (const float*)d_in[11];
    const float* bs   = (const float*)d_in[12];

    const int total = in_sizes[1] / 256;   // B*N
    const int BT    = out_size / 259;      // B*topk
    const int B     = BT / 128;            // topk = 128 for this problem
    const int N     = total / B;
    const int OUT   = in_sizes[11];        // 128

    float* ws_v      = (float*)d_ws;                       // 257 floats (pad 512)
    float* ws_scores = ws_v + 512;                         // total floats
    size_t off = ((size_t)(512 + total) * 4 + 255) & ~(size_t)255;
    unsigned long long* ws_bins = (unsigned long long*)((char*)d_ws + off);
    size_t off2 = (off + (size_t)B * 128 * 8 + 255) & ~(size_t)255;
    uint4* ws_wfrag = (uint4*)((char*)d_ws + off2);        // 16384 uint4 = 256KB

    prep_kernel<<<1, 256, 0, stream>>>(W2, b2, Ws, bs, ws_v, OUT);
    prep_w1frag<<<64, 256, 0, stream>>>(W1, ws_wfrag);
    init_bins<<<(B * 128 + 255) / 256, 256, 0, stream>>>(ws_bins, B * 128);
    score_kernel<<<(total + 127) / 128, 256, 0, stream>>>(
        desc, kpts, ws_wfrag, b1, g1, be1, Hp, Wp, ws_v, ws_scores, ws_bins, N, total);
    finalize_kernel<<<B, 256, 0, stream>>>(ws_scores, ws_bins, desc, kpts, tkp,
                                           (float*)d_out, B, N);
}